// Round 2
// baseline (91245.172 us; speedup 1.0000x reference)
//
#include <hip/hip_runtime.h>
#include <hip/hip_bf16.h>
#include <cstddef>

#define NN 32768
#define BM 64
#define BN 64
#define BK 32

// Generic fp32 GEMM: C[M,N] = concat(A1[idx],A2[idx]) @ W[N,K].T + b1 (+ b2)
// A1 width K1 (row-gathered via idx1 w/ stride istr if non-null), A2 width K2.
__global__ __launch_bounds__(256) void gemm_cat(
    const float* __restrict__ A1, const int* __restrict__ idx1,
    const float* __restrict__ A2, const int* __restrict__ idx2, int istr,
    int K1, int K2,
    const float* __restrict__ W, const float* __restrict__ b1,
    const float* __restrict__ b2,
    float* __restrict__ C, int M, int N)
{
    const int K = K1 + K2;
    __shared__ __align__(16) float As[BK][BM + 4];  // [k][m]
    __shared__ __align__(16) float Ws[BK][BN + 4];  // [k][n]
    const int tid = threadIdx.x;
    const int m0 = blockIdx.x * BM;
    const int n0 = blockIdx.y * BN;
    const int tx = tid & 15;        // 0..15 -> 4 cols each
    const int ty = tid >> 4;        // 0..15 -> 4 rows each
    float acc[4][4] = {};

    for (int k0 = 0; k0 < K; k0 += BK) {
        // ---- stage A tile (64 rows x 32 k), transposed to [k][m] ----
        #pragma unroll
        for (int p = 0; p < 2; ++p) {
            int q = tid + p * 256;       // 0..511
            int row = q >> 3;            // 0..63
            int kq = (q & 7) * 4;        // 0..28
            int gk = k0 + kq;
            int grow = m0 + row;
            const float* src;
            if (gk < K1) {
                int r = idx1 ? idx1[grow * istr] : grow;
                src = A1 + (size_t)r * K1 + gk;
            } else {
                int r = idx2 ? idx2[grow * istr] : grow;
                src = A2 + (size_t)r * K2 + (gk - K1);
            }
            float4 v = *(const float4*)src;
            As[kq + 0][row] = v.x; As[kq + 1][row] = v.y;
            As[kq + 2][row] = v.z; As[kq + 3][row] = v.w;
        }
        // ---- stage W tile (64 n-rows x 32 k), transposed to [k][n] ----
        #pragma unroll
        for (int p = 0; p < 2; ++p) {
            int q = tid + p * 256;
            int row = q >> 3;
            int kq = (q & 7) * 4;
            const float* src = W + (size_t)(n0 + row) * K + (k0 + kq);
            float4 v = *(const float4*)src;
            Ws[kq + 0][row] = v.x; Ws[kq + 1][row] = v.y;
            Ws[kq + 2][row] = v.z; Ws[kq + 3][row] = v.w;
        }
        __syncthreads();
        #pragma unroll
        for (int kk = 0; kk < BK; ++kk) {
            float4 a = *(const float4*)&As[kk][ty * 4];
            float4 b = *(const float4*)&Ws[kk][tx * 4];
            float av[4] = {a.x, a.y, a.z, a.w};
            float bv[4] = {b.x, b.y, b.z, b.w};
            #pragma unroll
            for (int i = 0; i < 4; ++i)
                #pragma unroll
                for (int jj = 0; jj < 4; ++jj)
                    acc[i][jj] += av[i] * bv[jj];
        }
        __syncthreads();
    }
    #pragma unroll
    for (int i = 0; i < 4; ++i) {
        int gr = m0 + ty * 4 + i;
        #pragma unroll
        for (int jj = 0; jj < 4; ++jj) {
            int gc = n0 + tx * 4 + jj;
            float bias = b1 ? b1[gc] : 0.f;
            if (b2) bias += b2[gc];
            C[(size_t)gr * N + gc] = acc[i][jj] + bias;
        }
    }
}

// Sequential LSTM scan over T steps. Single workgroup, 512 threads (8 waves).
// Thread j owns gate row j: g[j] = xg[t][j] + dot(Whh[j][:], h[:]).
// Gate order (PyTorch/JAX split): i, f, g, o in blocks of 128.
// __launch_bounds__(512, 2): 8 waves = 2 waves/SIMD -> VGPR cap 256, so the
// w[128] weight row stays in registers. (Round 1: default heuristic gave
// VGPR_Count=104 -> whole w[] spilled to scratch -> 3250 cyc/step.)
__global__ __launch_bounds__(512, 2) void lstm_scan(
    const float* __restrict__ xg,    // [T, 512] (includes bih+bhh)
    const float* __restrict__ Whh,   // [512, 128]
    float* __restrict__ hs,          // [T, 128]
    int T)
{
    __shared__ __align__(16) float h_lds[128];
    __shared__ float gact[512];
    const int j = threadIdx.x;

    // Whh row j -> 128 VGPRs
    float w[128];
    #pragma unroll
    for (int k4 = 0; k4 < 32; ++k4) {
        float4 v = *(const float4*)(Whh + (size_t)j * 128 + k4 * 4);
        w[k4 * 4 + 0] = v.x; w[k4 * 4 + 1] = v.y;
        w[k4 * 4 + 2] = v.z; w[k4 * 4 + 3] = v.w;
    }
    if (j < 128) h_lds[j] = 0.f;
    float c = 0.f;
    float xg_c = xg[j];
    float xg_n = xg[512 + j];
    const bool is_tanh = (j >= 256) && (j < 384);
    __syncthreads();

    for (int t = 0; t < T; ++t) {
        // prefetch xg for t+2 (hides latency under this step's compute)
        float xg_p = 0.f;
        if (t + 2 < T) xg_p = xg[(size_t)(t + 2) * 512 + j];

        float a0 = 0.f, a1 = 0.f, a2 = 0.f, a3 = 0.f;
        #pragma unroll
        for (int k4 = 0; k4 < 32; ++k4) {
            float4 h4 = *(const float4*)&h_lds[k4 * 4];  // broadcast read
            a0 += w[k4 * 4 + 0] * h4.x;
            a1 += w[k4 * 4 + 1] * h4.y;
            a2 += w[k4 * 4 + 2] * h4.z;
            a3 += w[k4 * 4 + 3] * h4.w;
        }
        float g = xg_c + ((a0 + a1) + (a2 + a3));

        // sigmoid(x) = 1/(1+e^-x); tanh(x) = 2*sigmoid(2x)-1
        float xx = is_tanh ? 2.f * g : g;
        float e = __expf(-xx);
        float s = __builtin_amdgcn_rcpf(1.f + e);
        float act = is_tanh ? (2.f * s - 1.f) : s;
        gact[j] = act;
        __syncthreads();   // gates ready; also ensures h_lds reads done

        if (j < 128) {
            float iv = gact[j];
            float fv = gact[j + 128];
            float gv = gact[j + 256];
            float ov = gact[j + 384];
            c = fv * c + iv * gv;
            float e2 = __expf(-2.f * c);
            float th = 2.f * __builtin_amdgcn_rcpf(1.f + e2) - 1.f;
            float h = ov * th;
            h_lds[j] = h;
            hs[(size_t)t * 128 + j] = h;
        }
        __syncthreads();   // h ready for next step
        xg_c = xg_n;
        xg_n = xg_p;
    }
}

extern "C" void kernel_launch(void* const* d_in, const int* in_sizes, int n_in,
                              void* d_out, int out_size, void* d_ws, size_t ws_size,
                              hipStream_t stream) {
    const float* inputs = (const float*)d_in[0];
    const int*   edges  = (const int*)d_in[1];     // [N,2] int32
    const float* in_W   = (const float*)d_in[2];   // [128,128]
    const float* in_b   = (const float*)d_in[3];   // [128]
    const float* out_W  = (const float*)d_in[4];   // [128,128]
    const float* out_b  = (const float*)d_in[5];   // [128]
    const float* edge_W = (const float*)d_in[6];   // [2,128,256]
    const float* edge_b = (const float*)d_in[7];   // [2,128]
    const float* Wih    = (const float*)d_in[8];   // [2,512,256]
    const float* Whh    = (const float*)d_in[9];   // [2,512,128]
    const float* bih    = (const float*)d_in[10];  // [2,512]
    const float* bhh    = (const float*)d_in[11];  // [2,512]
    float* out = (float*)d_out;

    float* ws = (float*)d_ws;
    float* nodesA = ws;                          // 32768*128
    float* nodesB = nodesA + (size_t)NN * 128;   // 32768*128
    float* edge_h = nodesB + (size_t)NN * 128;   // 32768*128
    float* xgbuf  = edge_h + (size_t)NN * 128;   // 32768*512

    dim3 blk(256);
    dim3 g128(NN / BM, 128 / BN);
    dim3 g512(NN / BM, 512 / BN);

    // nodes = inputs @ in_W.T + in_b
    gemm_cat<<<g128, blk, 0, stream>>>(inputs, nullptr, nullptr, nullptr, 1,
                                       128, 0, in_W, in_b, nullptr,
                                       nodesA, NN, 128);

    const float* cur = nodesA;
    float* nxt = nodesB;
    for (int r = 0; r < 2; ++r) {
        // edge_h = concat(nodes[src], nodes[dst]) @ edge_W[r].T + edge_b[r]
        gemm_cat<<<g128, blk, 0, stream>>>(cur, edges + 0, cur, edges + 1, 2,
                                           128, 128,
                                           edge_W + (size_t)r * 128 * 256,
                                           edge_b + (size_t)r * 128, nullptr,
                                           edge_h, NN, 128);
        // xg = concat(inputs, edge_h) @ Wih[r].T + bih[r] + bhh[r]
        gemm_cat<<<g512, blk, 0, stream>>>(inputs, nullptr, edge_h, nullptr, 1,
                                           128, 128,
                                           Wih + (size_t)r * 512 * 256,
                                           bih + (size_t)r * 512,
                                           bhh + (size_t)r * 512,
                                           xgbuf, NN, 512);
        // sequential LSTM scan
        lstm_scan<<<1, 512, 0, stream>>>(xgbuf, Whh + (size_t)r * 512 * 128,
                                         nxt, NN);
        const float* tmp = cur;
        cur = nxt;
        nxt = (float*)tmp;
    }

    // out = nodes @ out_W.T + out_b
    gemm_cat<<<g128, blk, 0, stream>>>(cur, nullptr, nullptr, nullptr, 1,
                                       128, 0, out_W, out_b, nullptr,
                                       out, NN, 128);
}

// Round 3
// 42597.659 us; speedup vs baseline: 2.1420x; 2.1420x over previous
//
#include <hip/hip_runtime.h>
#include <hip/hip_bf16.h>
#include <cstddef>

#define NN 32768
#define BM 64
#define BN 64
#define BK 32

typedef float f32x4 __attribute__((ext_vector_type(4)));
typedef short short8 __attribute__((ext_vector_type(8)));

__device__ inline unsigned short f2bf(float f) {
    unsigned u = __builtin_bit_cast(unsigned, f);
    unsigned r = (u + 0x7FFFu + ((u >> 16) & 1u)) >> 16;
    return (unsigned short)r;
}
__device__ inline float sigmoid_f(float x) {
    float e = __expf(-x);
    return __builtin_amdgcn_rcpf(1.f + e);
}
__device__ inline float tanh_f(float x) {
    float e = __expf(-2.f * x);
    return 2.f * __builtin_amdgcn_rcpf(1.f + e) - 1.f;
}

// Generic fp32 GEMM: C[M,N] = concat(A1[idx],A2[idx]) @ W[N,K].T + b1 (+ b2)
__global__ __launch_bounds__(256) void gemm_cat(
    const float* __restrict__ A1, const int* __restrict__ idx1,
    const float* __restrict__ A2, const int* __restrict__ idx2, int istr,
    int K1, int K2,
    const float* __restrict__ W, const float* __restrict__ b1,
    const float* __restrict__ b2,
    float* __restrict__ C, int M, int N)
{
    const int K = K1 + K2;
    __shared__ __align__(16) float As[BK][BM + 4];  // [k][m]
    __shared__ __align__(16) float Ws[BK][BN + 4];  // [k][n]
    const int tid = threadIdx.x;
    const int m0 = blockIdx.x * BM;
    const int n0 = blockIdx.y * BN;
    const int tx = tid & 15;
    const int ty = tid >> 4;
    float acc[4][4] = {};

    for (int k0 = 0; k0 < K; k0 += BK) {
        #pragma unroll
        for (int p = 0; p < 2; ++p) {
            int q = tid + p * 256;
            int row = q >> 3;
            int kq = (q & 7) * 4;
            int gk = k0 + kq;
            int grow = m0 + row;
            const float* src;
            if (gk < K1) {
                int r = idx1 ? idx1[grow * istr] : grow;
                src = A1 + (size_t)r * K1 + gk;
            } else {
                int r = idx2 ? idx2[grow * istr] : grow;
                src = A2 + (size_t)r * K2 + (gk - K1);
            }
            float4 v = *(const float4*)src;
            As[kq + 0][row] = v.x; As[kq + 1][row] = v.y;
            As[kq + 2][row] = v.z; As[kq + 3][row] = v.w;
        }
        #pragma unroll
        for (int p = 0; p < 2; ++p) {
            int q = tid + p * 256;
            int row = q >> 3;
            int kq = (q & 7) * 4;
            const float* src = W + (size_t)(n0 + row) * K + (k0 + kq);
            float4 v = *(const float4*)src;
            Ws[kq + 0][row] = v.x; Ws[kq + 1][row] = v.y;
            Ws[kq + 2][row] = v.z; Ws[kq + 3][row] = v.w;
        }
        __syncthreads();
        #pragma unroll
        for (int kk = 0; kk < BK; ++kk) {
            float4 a = *(const float4*)&As[kk][ty * 4];
            float4 b = *(const float4*)&Ws[kk][tx * 4];
            float av[4] = {a.x, a.y, a.z, a.w};
            float bv[4] = {b.x, b.y, b.z, b.w};
            #pragma unroll
            for (int i = 0; i < 4; ++i)
                #pragma unroll
                for (int jj = 0; jj < 4; ++jj)
                    acc[i][jj] += av[i] * bv[jj];
        }
        __syncthreads();
    }
    #pragma unroll
    for (int i = 0; i < 4; ++i) {
        int gr = m0 + ty * 4 + i;
        #pragma unroll
        for (int jj = 0; jj < 4; ++jj) {
            int gc = n0 + tx * 4 + jj;
            float bias = b1 ? b1[gc] : 0.f;
            if (b2) bias += b2[gc];
            C[(size_t)gr * N + gc] = acc[i][jj] + bias;
        }
    }
}

// MFMA LSTM scan. 1 block, 512 threads = 8 waves; wave w owns gate rows
// [w*64, w*64+64). Whh held in bf16 A-fragments (registers, loaded once).
// Per step: g = Whh@h via 16 mfma_f32_16x16x32_bf16 per wave, h replicated
// across B columns so all lanes' D values are valid; col-0 lanes write raw
// sums to LDS; threads 0..127 add xg (prefetched t+2), activate, update c/h.
// amdgpu_waves_per_eu(2,2): pin allocator to 2 waves/EU -> 256 VGPR budget
// (rounds 1-2: heuristic targeted 4 waves/EU -> 104 VGPRs -> spilled arrays).
__global__ __launch_bounds__(512)
__attribute__((amdgpu_waves_per_eu(2, 2)))
void lstm_scan(const float* __restrict__ xg,    // [T, 512] (includes biases)
               const float* __restrict__ Whh,   // [512, 128] fp32
               float* __restrict__ hs,          // [T, 128] fp32
               int T)
{
    __shared__ __align__(16) float gmv[512];          // raw Whh@h
    __shared__ __align__(16) unsigned short h16[128]; // h in bf16
    const int tid  = threadIdx.x;
    const int w    = tid >> 6;
    const int lane = tid & 63;
    const int m    = lane & 15;   // A-row within 16-row tile
    const int grp  = lane >> 4;   // k-group (A/B), row-group (C/D)

    // ---- A fragments: Whh[w*64 + mt*16 + m][kt*32 + grp*8 + j], bf16 ----
    short8 afrag[4][4];
    #pragma unroll
    for (int mt = 0; mt < 4; ++mt)
        #pragma unroll
        for (int kt = 0; kt < 4; ++kt) {
            const float* src = Whh + (size_t)(w * 64 + mt * 16 + m) * 128
                                   + kt * 32 + grp * 8;
            f32x4 v0 = *(const f32x4*)src;
            f32x4 v1 = *(const f32x4*)(src + 4);
            short8 s;
            s[0] = (short)f2bf(v0[0]); s[1] = (short)f2bf(v0[1]);
            s[2] = (short)f2bf(v0[2]); s[3] = (short)f2bf(v0[3]);
            s[4] = (short)f2bf(v1[0]); s[5] = (short)f2bf(v1[1]);
            s[6] = (short)f2bf(v1[2]); s[7] = (short)f2bf(v1[3]);
            afrag[mt][kt] = s;
        }

    float c = 0.f;
    f32x4 xg_c = {0.f, 0.f, 0.f, 0.f};
    f32x4 xg_n1 = {0.f, 0.f, 0.f, 0.f};
    f32x4 xg_n2 = {0.f, 0.f, 0.f, 0.f};
    if (tid < 128) {
        h16[tid] = 0;
        #pragma unroll
        for (int gi = 0; gi < 4; ++gi) xg_c[gi]  = xg[gi * 128 + tid];
        #pragma unroll
        for (int gi = 0; gi < 4; ++gi) xg_n1[gi] = xg[512 + gi * 128 + tid];
    }
    __syncthreads();

    for (int t = 0; t < T; ++t) {
        // ---- B fragments: h replicated across all 16 columns ----
        short8 bfrag[4];
        #pragma unroll
        for (int kt = 0; kt < 4; ++kt)
            bfrag[kt] = *(const short8*)&h16[kt * 32 + grp * 8];

        f32x4 acc[4];
        #pragma unroll
        for (int mt = 0; mt < 4; ++mt) acc[mt] = (f32x4){0.f, 0.f, 0.f, 0.f};
        #pragma unroll
        for (int kt = 0; kt < 4; ++kt)
            #pragma unroll
            for (int mt = 0; mt < 4; ++mt)
                acc[mt] = __builtin_amdgcn_mfma_f32_16x16x32_bf16(
                    afrag[mt][kt], bfrag[kt], acc[mt], 0, 0, 0);

        // col-0 lanes (0,16,32,48) write rows w*64+mt*16+grp*4 .. +3
        if (m == 0) {
            #pragma unroll
            for (int mt = 0; mt < 4; ++mt)
                *(f32x4*)&gmv[w * 64 + mt * 16 + grp * 4] = acc[mt];
        }

        // prefetch xg[t+2] (coalesced, hides HBM latency 2 steps deep)
        if (tid < 128 && t + 2 < T) {
            const float* p = xg + (size_t)(t + 2) * 512;
            #pragma unroll
            for (int gi = 0; gi < 4; ++gi) xg_n2[gi] = p[gi * 128 + tid];
        }
        __syncthreads();   // gmv ready; h16 reads drained

        if (tid < 128) {
            float iv = sigmoid_f(gmv[tid]       + xg_c[0]);
            float fv = sigmoid_f(gmv[tid + 128] + xg_c[1]);
            float gv = tanh_f   (gmv[tid + 256] + xg_c[2]);
            float ov = sigmoid_f(gmv[tid + 384] + xg_c[3]);
            c = fv * c + iv * gv;
            float h = ov * tanh_f(c);
            h16[tid] = f2bf(h);
            hs[(size_t)t * 128 + tid] = h;
            xg_c = xg_n1;
            xg_n1 = xg_n2;
        }
        __syncthreads();   // h16 ready for t+1
    }
}

extern "C" void kernel_launch(void* const* d_in, const int* in_sizes, int n_in,
                              void* d_out, int out_size, void* d_ws, size_t ws_size,
                              hipStream_t stream) {
    const float* inputs = (const float*)d_in[0];
    const int*   edges  = (const int*)d_in[1];     // [N,2] int32
    const float* in_W   = (const float*)d_in[2];   // [128,128]
    const float* in_b   = (const float*)d_in[3];   // [128]
    const float* out_W  = (const float*)d_in[4];   // [128,128]
    const float* out_b  = (const float*)d_in[5];   // [128]
    const float* edge_W = (const float*)d_in[6];   // [2,128,256]
    const float* edge_b = (const float*)d_in[7];   // [2,128]
    const float* Wih    = (const float*)d_in[8];   // [2,512,256]
    const float* Whh    = (const float*)d_in[9];   // [2,512,128]
    const float* bih    = (const float*)d_in[10];  // [2,512]
    const float* bhh    = (const float*)d_in[11];  // [2,512]
    float* out = (float*)d_out;

    float* ws = (float*)d_ws;
    float* nodesA = ws;                          // 32768*128
    float* nodesB = nodesA + (size_t)NN * 128;   // 32768*128
    float* edge_h = nodesB + (size_t)NN * 128;   // 32768*128
    float* xgbuf  = edge_h + (size_t)NN * 128;   // 32768*512

    dim3 blk(256);
    dim3 g128(NN / BM, 128 / BN);
    dim3 g512(NN / BM, 512 / BN);

    // nodes = inputs @ in_W.T + in_b
    gemm_cat<<<g128, blk, 0, stream>>>(inputs, nullptr, nullptr, nullptr, 1,
                                       128, 0, in_W, in_b, nullptr,
                                       nodesA, NN, 128);

    const float* cur = nodesA;
    float* nxt = nodesB;
    for (int r = 0; r < 2; ++r) {
        // edge_h = concat(nodes[src], nodes[dst]) @ edge_W[r].T + edge_b[r]
        gemm_cat<<<g128, blk, 0, stream>>>(cur, edges + 0, cur, edges + 1, 2,
                                           128, 128,
                                           edge_W + (size_t)r * 128 * 256,
                                           edge_b + (size_t)r * 128, nullptr,
                                           edge_h, NN, 128);
        // xg = concat(inputs, edge_h) @ Wih[r].T + bih[r] + bhh[r]
        gemm_cat<<<g512, blk, 0, stream>>>(inputs, nullptr, edge_h, nullptr, 1,
                                           128, 128,
                                           Wih + (size_t)r * 512 * 256,
                                           bih + (size_t)r * 512,
                                           bhh + (size_t)r * 512,
                                           xgbuf, NN, 512);
        // sequential LSTM scan (MFMA)
        lstm_scan<<<1, 512, 0, stream>>>(xgbuf, Whh + (size_t)r * 512 * 128,
                                         nxt, NN);
        const float* tmp = cur;
        cur = nxt;
        nxt = (float*)tmp;
    }

    // out = nodes @ out_W.T + out_b
    gemm_cat<<<g128, blk, 0, stream>>>(cur, nullptr, nullptr, nullptr, 1,
                                       128, 0, out_W, out_b, nullptr,
                                       out, NN, 128);
}